// Round 1
// baseline (529.574 us; speedup 1.0000x reference)
//
#include <hip/hip_runtime.h>
#include <math.h>

// Problem constants
#define NF 5
#define NB 8
#define NC 64
#define HW 16384
#define NK 320          // NF*NC
#define TS 64           // spatial tile width
#define KP 160          // W k-panel rows
#define PB 32           // blocks per batch in pass 1
#define TPB 8           // tiles per block (PB*TPB*TS == HW)
#define XST 68          // padded LDS row stride for X tile (multiple of 4, != 0 mod 32)

#define LDS_FLOATS (NK*XST + KP*NC + 4*NC*8)
#define LDS_BYTES  (LDS_FLOATS*4)

// ws layout (floats)
#define N_PARTIAL (NB*PB*8*NC)   // 131072
#define N_ALPHA   (NB*NK)        // 2560

// ---------------- k0: transpose origin_w [64][320] -> Wt [320][64] ----------------
__global__ void k0_wt(const float* __restrict__ W, float* __restrict__ Wt){
    int idx = blockIdx.x*256 + threadIdx.x;
    if (idx < NC*NK){
        int c = idx / NK;
        int k = idx - c*NK;
        Wt[k*NC + c] = W[idx];
    }
}

// ---------------- k1: per-(b,c) reductions E_i, N_i --------------------------------
// grid = NB*PB blocks of 256 threads; 1 block/CU (85+40+8 KB LDS).
// Thread (cg = tid&15, sg = tid>>4) computes origin for c = 4cg..4cg+3,
// s = tile_s0 + 4sg..4sg+3 via a 4x4 register tile, then accumulates
// E_i = sum origin*(X4-Xi), N_i = sum (X4-Xi)^2.
__global__ __launch_bounds__(256, 1) void k1_reduce(
    const float* __restrict__ inp, const float* __restrict__ bvec,
    const float* __restrict__ Wt, float* __restrict__ partial)
{
    extern __shared__ float lds[];
    float* Xs  = lds;                      // [320][XST]
    float* Ws  = lds + NK*XST;             // [160][64]
    float* red = lds + NK*XST + KP*NC;     // [4][64][8]

    const int tid = threadIdx.x;
    const int b = blockIdx.x / PB;
    const int p = blockIdx.x - b*PB;
    const int cg = tid & 15;
    const int sg = tid >> 4;
    const int c0 = cg << 2;

    float bias[4];
#pragma unroll
    for (int ci=0; ci<4; ++ci) bias[ci] = bvec[c0+ci];

    float accE[4][4], accN[4][4];
#pragma unroll
    for (int ci=0; ci<4; ++ci)
#pragma unroll
        for (int i=0; i<4; ++i){ accE[ci][i]=0.f; accN[ci][i]=0.f; }

    // X tile prefetch registers: 20 float4/thread = one 320x64 tile per block.
    // Row mapping: element j covers LDS row r = j*16+sg, columns 4cg..4cg+3.
    float4 pf[20];
    {
        const int s0 = p*TPB*TS;
#pragma unroll
        for (int j=0; j<20; ++j){
            int r = j*16 + sg;
            int off = (((r>>6)*NB + b)*NC + (r&63))*HW + s0 + (cg<<2);
            pf[j] = *reinterpret_cast<const float4*>(inp + off);
        }
    }

    for (int t=0; t<TPB; ++t){
        __syncthreads();                                   // prev tile's LDS reads done
        // ---- stage X tile from prefetch regs ----
#pragma unroll
        for (int j=0; j<20; ++j){
            int r = j*16 + sg;
            *reinterpret_cast<float4*>(&Xs[r*XST + (cg<<2)]) = pf[j];
        }
        // ---- stage W panel 0 (L2-resident) ----
        float4 w0r[10];
#pragma unroll
        for (int j=0; j<10; ++j){
            int kr = j*16 + sg;
            w0r[j] = *reinterpret_cast<const float4*>(&Wt[kr*NC + (cg<<2)]);
        }
#pragma unroll
        for (int j=0; j<10; ++j){
            int kr = j*16 + sg;
            *reinterpret_cast<float4*>(&Ws[kr*NC + (cg<<2)]) = w0r[j];
        }
        // ---- issue W panel 1 loads BEFORE the HBM prefetch: vmcnt retires
        //      in order, so panel-1 ds_writes must not wait on the X stream ----
        float4 w1r[10];
#pragma unroll
        for (int j=0; j<10; ++j){
            int kr = j*16 + sg;
            w1r[j] = *reinterpret_cast<const float4*>(&Wt[(KP+kr)*NC + (cg<<2)]);
        }
        __syncthreads();                                   // X + W0 visible
        // ---- prefetch next X tile (overlaps both GEMM phases) ----
        if (t+1 < TPB){
            const int s0 = (p*TPB + t + 1)*TS;
#pragma unroll
            for (int j=0; j<20; ++j){
                int r = j*16 + sg;
                int off = (((r>>6)*NB + b)*NC + (r&63))*HW + s0 + (cg<<2);
                pf[j] = *reinterpret_cast<const float4*>(inp + off);
            }
        }
        // ---- GEMM phase 0: k = 0..159 ----
        float acc[4][4];
#pragma unroll
        for (int ci=0; ci<4; ++ci)
#pragma unroll
            for (int si=0; si<4; ++si) acc[ci][si]=0.f;

        const float* Xb0 = Xs + (sg<<2);
        const float* Wb  = Ws + c0;
#pragma unroll 4
        for (int k=0; k<KP; ++k){
            float4 wv = *reinterpret_cast<const float4*>(Wb + k*NC);
            float4 xv = *reinterpret_cast<const float4*>(Xb0 + k*XST);
            float wr[4]={wv.x,wv.y,wv.z,wv.w};
            float xr[4]={xv.x,xv.y,xv.z,xv.w};
#pragma unroll
            for (int ci=0; ci<4; ++ci)
#pragma unroll
                for (int si=0; si<4; ++si)
                    acc[ci][si] = fmaf(wr[ci], xr[si], acc[ci][si]);
        }
        __syncthreads();                                   // panel-0 reads done
#pragma unroll
        for (int j=0; j<10; ++j){
            int kr = j*16 + sg;
            *reinterpret_cast<float4*>(&Ws[kr*NC + (cg<<2)]) = w1r[j];
        }
        __syncthreads();                                   // panel 1 visible
        // ---- GEMM phase 1: k = 160..319 ----
        const float* Xb1 = Xs + KP*XST + (sg<<2);
#pragma unroll 4
        for (int k=0; k<KP; ++k){
            float4 wv = *reinterpret_cast<const float4*>(Wb + k*NC);
            float4 xv = *reinterpret_cast<const float4*>(Xb1 + k*XST);
            float wr[4]={wv.x,wv.y,wv.z,wv.w};
            float xr[4]={xv.x,xv.y,xv.z,xv.w};
#pragma unroll
            for (int ci=0; ci<4; ++ci)
#pragma unroll
                for (int si=0; si<4; ++si)
                    acc[ci][si] = fmaf(wr[ci], xr[si], acc[ci][si]);
        }
        // ---- reduction accumulate for this tile ----
#pragma unroll
        for (int ci=0; ci<4; ++ci){
            const int c = c0 + ci;
            float4 x4 = *reinterpret_cast<const float4*>(&Xs[(4*NC + c)*XST + (sg<<2)]);
            float o0 = acc[ci][0]+bias[ci], o1 = acc[ci][1]+bias[ci];
            float o2 = acc[ci][2]+bias[ci], o3 = acc[ci][3]+bias[ci];
#pragma unroll
            for (int i=0; i<4; ++i){
                float4 xi = *reinterpret_cast<const float4*>(&Xs[(i*NC + c)*XST + (sg<<2)]);
                float d0 = x4.x-xi.x, d1 = x4.y-xi.y, d2 = x4.z-xi.z, d3 = x4.w-xi.w;
                accN[ci][i] += d0*d0 + d1*d1 + d2*d2 + d3*d3;
                accE[ci][i] += o0*d0 + o1*d1 + o2*d2 + o3*d3;
            }
        }
    }

    // ---- cross-thread reduction: sum over the 16 sg threads per c ----
#pragma unroll
    for (int ci=0; ci<4; ++ci)
#pragma unroll
        for (int i=0; i<4; ++i){
            float e = accE[ci][i], n = accN[ci][i];
            e += __shfl_xor(e, 16, 64); e += __shfl_xor(e, 32, 64);
            n += __shfl_xor(n, 16, 64); n += __shfl_xor(n, 32, 64);
            accE[ci][i]=e; accN[ci][i]=n;
        }
    if ((tid & 48) == 0){               // one rep per (wave, cg)
        int wv = tid >> 6;
#pragma unroll
        for (int ci=0; ci<4; ++ci){
            int c = c0+ci;
#pragma unroll
            for (int i=0; i<4; ++i){
                red[(wv*NC + c)*8 + i]     = accE[ci][i];
                red[(wv*NC + c)*8 + 4 + i] = accN[ci][i];
            }
        }
    }
    __syncthreads();
    if (tid < NC){
#pragma unroll
        for (int q=0; q<8; ++q){
            float s = red[(0*NC+tid)*8+q] + red[(1*NC+tid)*8+q]
                    + red[(2*NC+tid)*8+q] + red[(3*NC+tid)*8+q];
            partial[((b*PB + p)*8 + q)*NC + tid] = s;
        }
    }
}

// ---------------- k2: finalize coef -> alpha ----------------
__global__ void k2_coef(const float* __restrict__ partial, const float* __restrict__ out_w,
                        float* __restrict__ alpha)
{
    int tid = threadIdx.x;          // 512 = NB*NC
    int b = tid >> 6, c = tid & 63;
    float E[4] = {0,0,0,0}, N[4] = {0,0,0,0};
    for (int p=0; p<PB; ++p){
        const float* base = partial + ((b*PB + p)*8)*NC + c;
#pragma unroll
        for (int i=0; i<4; ++i) E[i] += base[i*NC];
#pragma unroll
        for (int i=0; i<4; ++i) N[i] += base[(4+i)*NC];
    }
    float w1 = out_w[c], w2 = out_w[NC + c];
    float csum = 0.f;
#pragma unroll
    for (int i=0; i<4; ++i){
        float nc = fmaxf(sqrtf(N[i]), 1e-12f);
        float coef = E[i] / (nc*nc);
        alpha[b*NK + i*NC + c] = -w1*coef;
        csum += coef;
    }
    alpha[b*NK + 4*NC + c] = w1*csum + w2;
}

// ---------------- k3: y[b,s] = sum_r alpha[b,r]*inp[r,b,s] + out_b ----------------
__global__ __launch_bounds__(256) void k3_out(const float* __restrict__ inp,
        const float* __restrict__ alpha, const float* __restrict__ out_b,
        float* __restrict__ y)
{
    int b  = blockIdx.x >> 5;
    int sb = blockIdx.x & 31;
    int s  = (sb*256 + threadIdx.x)*2;
    const float* al = alpha + b*NK;     // wave-uniform -> s_load
    float a0 = out_b[0], a1 = a0;
    const float* base = inp + b*NC*HW + s;
#pragma unroll 1
    for (int f=0; f<NF; ++f){
        const float* fb = base + f*NB*NC*HW;
#pragma unroll 8
        for (int c=0; c<NC; ++c){
            float2 v = *reinterpret_cast<const float2*>(fb + c*HW);
            float w = al[f*NC + c];
            a0 = fmaf(w, v.x, a0);
            a1 = fmaf(w, v.y, a1);
        }
    }
    *reinterpret_cast<float2*>(y + b*HW + s) = make_float2(a0, a1);
}

extern "C" void kernel_launch(void* const* d_in, const int* in_sizes, int n_in,
                              void* d_out, int out_size, void* d_ws, size_t ws_size,
                              hipStream_t stream)
{
    const float* inp      = (const float*)d_in[0];
    const float* origin_w = (const float*)d_in[1];
    const float* origin_b = (const float*)d_in[2];
    const float* out_w    = (const float*)d_in[3];
    const float* out_b    = (const float*)d_in[4];
    float* y  = (float*)d_out;
    float* ws = (float*)d_ws;

    float* partial = ws;                          // 131072 floats
    float* alpha   = ws + N_PARTIAL;              // 2560 floats
    float* Wt      = ws + N_PARTIAL + N_ALPHA;    // 20480 floats

    // allow >64KB dynamic LDS (gfx950 has 160 KiB/CU); harmless if not needed
    (void)hipFuncSetAttribute(reinterpret_cast<const void*>(k1_reduce),
                              hipFuncAttributeMaxDynamicSharedMemorySize, LDS_BYTES);

    k0_wt    <<<(NC*NK + 255)/256, 256, 0, stream>>>(origin_w, Wt);
    k1_reduce<<<NB*PB, 256, LDS_BYTES, stream>>>(inp, origin_b, Wt, partial);
    k2_coef  <<<1, NB*NC, 0, stream>>>(partial, out_w, alpha);
    k3_out   <<<NB*32, 256, 0, stream>>>(inp, alpha, out_b, y);
}

// Round 2
// 440.782 us; speedup vs baseline: 1.2014x; 1.2014x over previous
//
#include <hip/hip_runtime.h>
#include <math.h>

// Problem constants
#define NF 5
#define NB 8
#define NC 64
#define HW 16384
#define NK 320          // NF*NC
#define FSTRIDE (NB*NC*HW)   // elements per frame = 8388608

// ws layout (floats)
#define EN_FLOATS    (NB*NC*8)   // 4096: per (b,c): E0..E3, N0..N3
#define ALPHA_FLOATS (NB*NK)     // 2560
#define OT_STRIDE 65             // LDS row stride: bank = (65c + s)%32 = (c+s)%32 -> conflict-free

// ---------------- k0: transpose origin_w [64][320] -> Wt [320][64] ----------------
__global__ void k0_wt(const float* __restrict__ W, float* __restrict__ Wt){
    int idx = blockIdx.x*256 + threadIdx.x;
    if (idx < NC*NK){
        int c = idx / NK;
        int k = idx - c*NK;
        Wt[k*NC + c] = W[idx];   // Wt row k = 64 contiguous c -> s_load_dwordx16 friendly
    }
}

// ---------------- k1: fused GEMM + E/N reduction, wave-independent ----------------
// grid = 512 blocks x 256 thr; wave w handles tile t = blk*4+w (64 spatial positions).
// Phase A (GEMM): lane = s. acc[c] = bias[c] + sum_k Wt[k][c]*X[k,s].
//   W is wave-uniform -> SGPR; X loads are 1 dword/lane, coalesced, read once.
// Phase B: per c-half, transpose o through a per-wave 8.3KB LDS buffer,
//   lane = (c_local, s_half), re-read X rows (L1-friendly), accumulate E/N,
//   combine s-halves via shfl_xor(32), atomicAdd into global EN.
__global__ __launch_bounds__(256, 2) void k1_fused(
    const float* __restrict__ inp, const float* __restrict__ Wt,
    const float* __restrict__ bias, float* __restrict__ EN)
{
    __shared__ float oT[4][32*OT_STRIDE];   // per-wave private buffers, 33.3 KB total

    const int tid  = threadIdx.x;
    const int w    = tid >> 6;
    const int lane = tid & 63;
    const int t    = blockIdx.x*4 + w;      // 0..2047
    const int b    = t >> 8;                // 256 tiles per batch
    const int s0   = (t & 255) << 6;        // tile base spatial
    float* obuf = oT[w];

    // ---- Phase A: GEMM into acc[64] ----
    float acc[64];
#pragma unroll
    for (int c=0; c<64; ++c) acc[c] = bias[c];          // uniform -> s_load

    for (int f=0; f<NF; ++f){
        const float* fb = inp + (size_t)(f*NB + b)*NC*HW + s0 + lane;
        const float* wr = Wt + f*64*NC;
#pragma unroll 4
        for (int k=0; k<64; ++k){
            float x = fb[(size_t)k*HW];                 // coalesced, 256B/wave
#pragma unroll
            for (int c=0; c<64; ++c)
                acc[c] = fmaf(wr[k*NC + c], x, acc[c]); // W uniform -> scalar operand
        }
    }

    // ---- Phase B: E/N accumulation ----
    const int cl = lane & 31;       // c within half
    const int sh = lane >> 5;       // s-half (0: s0..s0+31, 1: s0+32..s0+63)
    float accE[2][4], accN[2][4];
#pragma unroll
    for (int h=0; h<2; ++h)
#pragma unroll
        for (int i=0; i<4; ++i){ accE[h][i]=0.f; accN[h][i]=0.f; }

#pragma unroll 1
    for (int h=0; h<2; ++h){
        // transpose-write this c-half: lane s writes o[c] to row c
        // addr = j*65 + lane -> banks (j+lane)%32: conflict-free
#pragma unroll
        for (int j=0; j<32; ++j)
            obuf[j*OT_STRIDE + lane] = acc[h*32 + j];
        // same-wave RAW through LDS: compiler inserts lgkmcnt wait; no barrier needed

        const int c = h*32 + cl;
        const float* orow = obuf + cl*OT_STRIDE + sh*32;
        const float* base = inp + ((size_t)b*NC + c)*HW + s0 + sh*32;
        const float* x4r  = base + (size_t)4*FSTRIDE;

#pragma unroll
        for (int j4=0; j4<8; ++j4){
            float4 x4 = *reinterpret_cast<const float4*>(x4r + j4*4);
            float o0 = orow[j4*4+0], o1 = orow[j4*4+1];
            float o2 = orow[j4*4+2], o3 = orow[j4*4+3];
#pragma unroll
            for (int i=0; i<4; ++i){
                float4 xi = *reinterpret_cast<const float4*>(base + (size_t)i*FSTRIDE + j4*4);
                float d0 = x4.x-xi.x, d1 = x4.y-xi.y, d2 = x4.z-xi.z, d3 = x4.w-xi.w;
                accN[h][i] = fmaf(d0,d0, fmaf(d1,d1, fmaf(d2,d2, fmaf(d3,d3, accN[h][i]))));
                accE[h][i] = fmaf(o0,d0, fmaf(o1,d1, fmaf(o2,d2, fmaf(o3,d3, accE[h][i]))));
            }
        }
    }

    // combine the two s-halves (lanes l and l+32 hold same (c,i))
#pragma unroll
    for (int h=0; h<2; ++h)
#pragma unroll
        for (int i=0; i<4; ++i){
            accE[h][i] += __shfl_xor(accE[h][i], 32, 64);
            accN[h][i] += __shfl_xor(accN[h][i], 32, 64);
        }

    if (lane < 32){
        float* enb = EN + (size_t)b*NC*8;
#pragma unroll
        for (int h=0; h<2; ++h){
            int c = h*32 + cl;
#pragma unroll
            for (int i=0; i<4; ++i){
                atomicAdd(&enb[c*8 + i],     accE[h][i]);
                atomicAdd(&enb[c*8 + 4 + i], accN[h][i]);
            }
        }
    }
}

// ---------------- k2: finalize coef -> alpha ----------------
__global__ void k2_coef(const float* __restrict__ EN, const float* __restrict__ out_w,
                        float* __restrict__ alpha)
{
    int tid = threadIdx.x;          // 512 = NB*NC
    int b = tid >> 6, c = tid & 63;
    const float* e = EN + (b*NC + c)*8;
    float w1 = out_w[c], w2 = out_w[NC + c];
    float csum = 0.f;
#pragma unroll
    for (int i=0; i<4; ++i){
        float n = fmaxf(sqrtf(e[4+i]), 1e-12f);
        float coef = e[i] / (n*n);
        alpha[b*NK + i*NC + c] = -w1*coef;
        csum += coef;
    }
    alpha[b*NK + 4*NC + c] = w1*csum + w2;
}

// ---------------- k3: y[b,s] = sum_r alpha[b,r]*inp[r,b,s] + out_b ----------------
// grid 512 x 256: 2 blocks/CU, 8 waves/CU, pure streaming.
__global__ __launch_bounds__(256) void k3_out(const float* __restrict__ inp,
        const float* __restrict__ alpha, const float* __restrict__ out_b,
        float* __restrict__ y)
{
    int b = blockIdx.x >> 6;
    int s = ((blockIdx.x & 63) << 8) + threadIdx.x;
    const float* al = alpha + b*NK;            // wave-uniform -> s_load
    float a = out_b[0];
    const float* base = inp + (size_t)b*NC*HW + s;
#pragma unroll
    for (int f=0; f<NF; ++f){
        const float* fb = base + (size_t)f*FSTRIDE;
#pragma unroll 8
        for (int c=0; c<NC; ++c)
            a = fmaf(al[f*NC + c], fb[(size_t)c*HW], a);
    }
    y[(size_t)b*HW + s] = a;
}

extern "C" void kernel_launch(void* const* d_in, const int* in_sizes, int n_in,
                              void* d_out, int out_size, void* d_ws, size_t ws_size,
                              hipStream_t stream)
{
    const float* inp      = (const float*)d_in[0];
    const float* origin_w = (const float*)d_in[1];
    const float* origin_b = (const float*)d_in[2];
    const float* out_w    = (const float*)d_in[3];
    const float* out_b    = (const float*)d_in[4];
    float* y  = (float*)d_out;
    float* ws = (float*)d_ws;

    float* EN    = ws;                              // 4096 floats
    float* alpha = ws + EN_FLOATS;                  // 2560 floats
    float* Wt    = ws + EN_FLOATS + ALPHA_FLOATS;   // 20480 floats

    hipMemsetAsync(EN, 0, EN_FLOATS*sizeof(float), stream);
    k0_wt   <<<(NC*NK + 255)/256, 256, 0, stream>>>(origin_w, Wt);
    k1_fused<<<512, 256, 0, stream>>>(inp, Wt, origin_b, EN);
    k2_coef <<<1, NB*NC, 0, stream>>>(EN, out_w, alpha);
    k3_out  <<<512, 256, 0, stream>>>(inp, alpha, out_b, y);
}